// Round 4
// baseline (561.528 us; speedup 1.0000x reference)
//
#include <hip/hip_runtime.h>
#include <math.h>

#define NN 512
#define NBC 128   // B*2

typedef __attribute__((ext_vector_type(8))) __bf16 v8bf;
typedef __attribute__((ext_vector_type(4))) float v4f;

// round-to-nearest-even bf16 split: v = hi + lo (+O(2^-17) rel)
__device__ __forceinline__ void bsplit(float v, unsigned short& h, unsigned short& l) {
    unsigned u  = __builtin_bit_cast(unsigned, v);
    unsigned hb = (u + 0x7fffu + ((u >> 16) & 1u)) & 0xffff0000u;
    float hf    = __builtin_bit_cast(float, hb);
    h = (unsigned short)(hb >> 16);
    float lof   = v - hf;
    unsigned ul = __builtin_bit_cast(unsigned, lof);
    l = (unsigned short)((ul + 0x7fffu + ((ul >> 16) & 1u)) >> 16);
}

// Fragment-tile layout for an [n][k] operand matrix (n = MFMA 16-dim, k = K):
//   tile = (n/16)*(Kext/32) + (k/32); lane = (n%16) + 16*((k%32)/8); elem = k%8
//   addr(shorts) = tile*512 + lane*8 + elem
// A wave's MFMA fragment load (n = base+m0, k = ko+quad*8) is then ONE
// contiguous 1KB global_load_dwordx4 at tile*512 + lane*8.
__device__ __forceinline__ size_t fragaddr(int n, int k, int kext) {
    return ((size_t)(n >> 4) * (kext >> 5) + (k >> 5)) * 512
         + (size_t)(((n & 15) + 16 * ((k >> 3) & 3)) * 8 + (k & 7));
}

// ---------------- degree: dinv[bc][i] = rsqrt(1 + sum_j adj[bc][i][j]) -----
__global__ __launch_bounds__(256) void k_rowsum(const float* __restrict__ adj,
                                                float* __restrict__ dinv) {
    int wave = blockIdx.x * 4 + (threadIdx.x >> 6);
    int lane = threadIdx.x & 63;
    const float4* row = (const float4*)(adj + (size_t)wave * NN);
    float4 v0 = row[lane], v1 = row[lane + 64];
    float s = v0.x + v0.y + v0.z + v0.w + v1.x + v1.y + v1.z + v1.w;
    #pragma unroll
    for (int off = 32; off; off >>= 1) s += __shfl_down(s, off, 64);
    if (lane == 0) dinv[wave] = rsqrtf(1.0f + s);
}

// ---------------- An = D(adj+I)D  ->  bf16 hi/lo planes, fragment order -----
// Block = 256 threads = 4 waves = 4 rows; wave handles one full row (2KB read,
// lane covers 8 contiguous floats).  Writes one 16B fragment chunk per plane;
// consecutive blocks densely cover each 16KB tile region so L2 merges the
// 256B-strided chunks into full lines.
__global__ __launch_bounds__(256) void k_convert(const float* __restrict__ adj,
    const float* __restrict__ dinv, unsigned short* __restrict__ anh,
    unsigned short* __restrict__ anl)
{
    const int row4 = blockIdx.x;           // 16384 = 128 bc * 128 row-quads
    const int bc = row4 >> 7;
    const int wv = threadIdx.x >> 6, lane = threadIdx.x & 63;
    const int i = (row4 & 127) * 4 + wv;
    const int it = i >> 4;
    const int j0 = lane * 8;
    const float* arow = adj + ((size_t)bc * NN + i) * NN + j0;
    float4 a0 = *(const float4*)(arow);
    float4 a1 = *(const float4*)(arow + 4);
    const float di = dinv[bc * NN + i];
    const float4 d0 = *(const float4*)(dinv + bc * NN + j0);
    const float4 d1 = *(const float4*)(dinv + bc * NN + j0 + 4);
    float av[8] = { a0.x, a0.y, a0.z, a0.w, a1.x, a1.y, a1.z, a1.w };
    float dj[8] = { d0.x, d0.y, d0.z, d0.w, d1.x, d1.y, d1.z, d1.w };
    unsigned pw[4], qw[4];
    #pragma unroll
    for (int q = 0; q < 4; ++q) {
        unsigned short h0, l0, h1, l1;
        float u0 = di * dj[2*q]     * (av[2*q]     + ((j0 + 2*q)     == i ? 1.f : 0.f));
        float u1 = di * dj[2*q + 1] * (av[2*q + 1] + ((j0 + 2*q + 1) == i ? 1.f : 0.f));
        bsplit(u0, h0, l0); bsplit(u1, h1, l1);
        pw[q] = (unsigned)h0 | ((unsigned)h1 << 16);
        qw[q] = (unsigned)l0 | ((unsigned)l1 << 16);
    }
    size_t oa = (((size_t)(bc * 32 + it)) * 16 + (j0 >> 5)) * 512
              + (size_t)(((i & 15) + 16 * ((j0 >> 3) & 3)) * 8);
    uint4 ph; ph.x = pw[0]; ph.y = pw[1]; ph.z = pw[2]; ph.w = pw[3];
    uint4 pl; pl.x = qw[0]; pl.y = qw[1]; pl.z = qw[2]; pl.w = qw[3];
    *(uint4*)(anh + oa) = ph;
    *(uint4*)(anl + oa) = pl;
}

// ---------------- weight prep: dst = split(w[p][h]) in fragment order -------
struct WJob  { const float* w; unsigned short* dh; unsigned short* dl; int HI; int HO; int HOP; };
struct WJobs { WJob j[8]; };
__global__ __launch_bounds__(256) void k_wprep(WJobs jobs) {
    WJob jb = jobs.j[blockIdx.y];
    int idx = blockIdx.x * 256 + threadIdx.x;
    if (idx >= jb.HOP * jb.HI) return;
    int h = idx / jb.HI, p = idx % jb.HI;
    float v = (h < jb.HO) ? jb.w[p * jb.HO + h] : 0.f;
    unsigned short hh, ll; bsplit(v, hh, ll);
    size_t oa = fragaddr(h, p, jb.HI);
    jb.dh[oa] = hh; jb.dl[oa] = ll;
}

// ---------------- MFMA layer: X = act(An @ Z + b) ---------------------------
// LDS-free, barrier-free fragment-direct GEMM.  Operands stored in fragment-
// tile order -> every A/B fragment is one coalesced 1KB global_load_dwordx4.
// Block = 64 rows x BN cols, 4 waves (2x2 for BN>=32, 4x1 for BN=16).
// Latency hiding: TLP (4 blocks/CU, independent wave phases) + unroll-2 ILP.
// 3-term split: Ah@Zh + Ah@Zl + Al@Zh (order preserved -> bit-identical).
template<int BN, int OUTW, bool SHAREDZ, bool ACT, bool WBF, int MINW>
__global__ __launch_bounds__(256, MINW) void k_mfma(
    const unsigned short* __restrict__ anh_, const unsigned short* __restrict__ anl_,
    const unsigned short* __restrict__ zh_,  const unsigned short* __restrict__ zl_,
    const float* __restrict__ bp, const float* __restrict__ bn,
    float* __restrict__ xf, unsigned short* __restrict__ xh, unsigned short* __restrict__ xl)
{
    constexpr int WC = (BN >= 32) ? 2 : 1;        // col-split waves
    constexpr int WR = 4 / WC;                    // row-split waves
    constexpr int RF = 64 / (WR * 16);            // 16-row frags per wave
    constexpr int C  = (BN / WC) / 16;            // 16-col frags per wave
    const int bc = blockIdx.y, rb = blockIdx.x;
    const int t = threadIdx.x, w = t >> 6, lane = t & 63;
    const int m0 = lane & 15, quad = lane >> 4;
    const int wr = w / WC, wc = w % WC;
    const int s = SHAREDZ ? (bc & 1) : bc;

    const unsigned short* pah[RF]; const unsigned short* pal[RF];
    #pragma unroll
    for (int r = 0; r < RF; ++r) {
        int it = rb * 4 + wr * RF + r;
        size_t b0 = ((size_t)(bc * 32 + it)) * 8192 + (size_t)(lane * 8);
        pah[r] = anh_ + b0; pal[r] = anl_ + b0;
    }
    const unsigned short* pzh[C]; const unsigned short* pzl[C];
    #pragma unroll
    for (int c = 0; c < C; ++c) {
        int nt = (wc * (BN / WC)) / 16 + c;
        size_t b0 = ((size_t)(s * (BN / 16) + nt)) * 8192 + (size_t)(lane * 8);
        pzh[c] = zh_ + b0; pzl[c] = zl_ + b0;
    }

    v4f acc[RF][C];
    #pragma unroll
    for (int r = 0; r < RF; ++r)
        #pragma unroll
        for (int c = 0; c < C; ++c) acc[r][c] = (v4f){0.f, 0.f, 0.f, 0.f};

    #pragma unroll 2
    for (int kb = 0; kb < 16; ++kb) {
        const int ko = kb * 512;
        v8bf zfh[C], zfl[C];
        #pragma unroll
        for (int c = 0; c < C; ++c) {
            zfh[c] = *(const v8bf*)(pzh[c] + ko);
            zfl[c] = *(const v8bf*)(pzl[c] + ko);
        }
        v8bf ahh[RF], all_[RF];
        #pragma unroll
        for (int r = 0; r < RF; ++r) {
            ahh[r]  = *(const v8bf*)(pah[r] + ko);
            all_[r] = *(const v8bf*)(pal[r] + ko);
        }
        #pragma unroll
        for (int r = 0; r < RF; ++r) {
            #pragma unroll
            for (int c = 0; c < C; ++c) {
                acc[r][c] = __builtin_amdgcn_mfma_f32_16x16x32_bf16(ahh[r],  zfh[c], acc[r][c], 0, 0, 0);
                acc[r][c] = __builtin_amdgcn_mfma_f32_16x16x32_bf16(ahh[r],  zfl[c], acc[r][c], 0, 0, 0);
                acc[r][c] = __builtin_amdgcn_mfma_f32_16x16x32_bf16(all_[r], zfh[c], acc[r][c], 0, 0, 0);
            }
        }
    }

    const float* bias = (bc & 1) ? bn : bp;
    #pragma unroll
    for (int r = 0; r < RF; ++r)
        #pragma unroll
        for (int c = 0; c < C; ++c) {
            int col = wc * (BN / WC) + c * 16 + m0;
            if (OUTW < BN && col >= OUTW) continue;
            float bv = bias[col];
            #pragma unroll
            for (int reg = 0; reg < 4; ++reg) {
                int row = rb * 64 + wr * (RF * 16) + r * 16 + quad * 4 + reg;
                float v = acc[r][c][reg] + bv;
                if (ACT) v = v >= 0.f ? v : 0.2f * v;
                if (xf) xf[((size_t)bc * NN + row) * OUTW + col] = v;
                if (WBF) {
                    unsigned short hh, ll; bsplit(v, hh, ll);
                    size_t fo = (((size_t)(bc * 32) + (row >> 4)) * (OUTW / 32) + (col >> 5)) * 512
                              + (size_t)(((row & 15) + 16 * ((col >> 3) & 3)) * 8 + (col & 7));
                    xh[fo] = hh; xl[fo] = ll;
                }
            }
        }
}

// ---------------- MFMA Z-gemm: Zt[h][j] = sum_p W[p][h] X[j][p] -------------
// A = Wt fragment-tile [s][h][p], B = X fragment-tile [bc][j][p];
// output Zt written in fragment-tile order [bc][h-tiles][j] for next k_mfma.
template<int HI, int HOP>
__global__ __launch_bounds__(256) void k_zgemm(
    const unsigned short* __restrict__ wth, const unsigned short* __restrict__ wtl,
    const unsigned short* __restrict__ xh_, const unsigned short* __restrict__ xl_,
    unsigned short* __restrict__ zh_, unsigned short* __restrict__ zl_)
{
    constexpr int MT = HOP / 16, JW = 4 / MT, NT = 8 / JW;
    const int bc = blockIdx.y, jb = blockIdx.x;
    const int t = threadIdx.x, w = t >> 6, lane = t & 63;
    const int m0 = lane & 15, quad = lane >> 4;
    const int mt = w % MT, jseg = w / MT;
    const int n0 = jb * 128 + jseg * (128 / JW);
    const int s = bc & 1;
    size_t wb = ((size_t)(s * MT + mt)) * (size_t)((HI / 32) * 512) + (size_t)(lane * 8);
    const unsigned short* pw_h = wth + wb;
    const unsigned short* pw_l = wtl + wb;
    const unsigned short* pxh[NT]; const unsigned short* pxl[NT];
    #pragma unroll
    for (int c = 0; c < NT; ++c) {
        size_t xb = ((size_t)(bc * 32 + (n0 >> 4) + c)) * (size_t)((HI / 32) * 512) + (size_t)(lane * 8);
        pxh[c] = xh_ + xb; pxl[c] = xl_ + xb;
    }
    v4f acc[NT];
    #pragma unroll
    for (int c = 0; c < NT; ++c) acc[c] = (v4f){0.f, 0.f, 0.f, 0.f};
    #pragma unroll
    for (int ks = 0; ks < HI / 32; ++ks) {
        const int ko = ks * 512;
        v8bf awh = *(const v8bf*)(pw_h + ko);
        v8bf awl = *(const v8bf*)(pw_l + ko);
        #pragma unroll
        for (int c = 0; c < NT; ++c) {
            v8bf bxh = *(const v8bf*)(pxh[c] + ko);
            v8bf bxl = *(const v8bf*)(pxl[c] + ko);
            acc[c] = __builtin_amdgcn_mfma_f32_16x16x32_bf16(awh, bxh, acc[c], 0, 0, 0);
            acc[c] = __builtin_amdgcn_mfma_f32_16x16x32_bf16(awh, bxl, acc[c], 0, 0, 0);
            acc[c] = __builtin_amdgcn_mfma_f32_16x16x32_bf16(awl, bxh, acc[c], 0, 0, 0);
        }
    }
    #pragma unroll
    for (int c = 0; c < NT; ++c) {
        int j = n0 + c * 16 + m0;
        int jt = j >> 5, jg = (j >> 3) & 3, je = j & 7;
        #pragma unroll
        for (int reg = 0; reg < 4; ++reg) {
            int h = mt * 16 + quad * 4 + reg;
            unsigned short hh, ll; bsplit(acc[c][reg], hh, ll);
            size_t oi = (((size_t)(bc * MT + mt)) * 16 + jt) * 512
                      + (size_t)(((h & 15) + 16 * jg) * 8 + je);
            zh_[oi] = hh; zl_[oi] = ll;
        }
    }
}

// ================= FALLBACK (R2 proven path, fp32 vector) ===================
template<int H, int HP, bool SHARED, bool ACT>
__global__ __launch_bounds__(256) void k_biggemm(
    const float* __restrict__ adj, const float* __restrict__ zcg,
    const float* __restrict__ wp, const float* __restrict__ wn,
    const float* __restrict__ bp, const float* __restrict__ bn,
    const float* __restrict__ dinv, float* __restrict__ xout)
{
    constexpr int CPT = HP / 16;
    constexpr int KT = 64;
    __shared__ float a_s[64 * 68];
    __shared__ float z_s[KT * H];
    const int bc = blockIdx.y;
    const int rt = blockIdx.x;
    const int t  = threadIdx.x;
    const int tx = t & 15, ty = t >> 4;
    const float* A    = adj + (size_t)bc * NN * NN + (size_t)rt * 64 * NN;
    const float* dloc = dinv + bc * NN;
    const float* ZG   = SHARED ? ((bc & 1) ? wn : wp) : (zcg + (size_t)bc * NN * H);
    const float* bias = (bc & 1) ? bn : bp;
    float acc[4][CPT];
    #pragma unroll
    for (int r = 0; r < 4; ++r)
        #pragma unroll
        for (int u = 0; u < CPT; ++u) acc[r][u] = 0.f;
    for (int kb = 0; kb < NN; kb += KT) {
        __syncthreads();
        #pragma unroll
        for (int l = 0; l < 4; ++l) {
            int idx = t + l * 256;
            int r = idx >> 4, q = idx & 15;
            float4 v = *(const float4*)(A + (size_t)r * NN + kb + q * 4);
            *(float4*)(a_s + r * 68 + q * 4) = v;
        }
        constexpr int NZ4 = KT * H / 4;
        for (int idx = t; idx < NZ4; idx += 256) {
            int k = idx / (H / 4), hq = idx % (H / 4);
            float4 v = *(const float4*)(ZG + (size_t)(kb + k) * H + hq * 4);
            if (SHARED) {
                float dk = dloc[kb + k];
                v.x *= dk; v.y *= dk; v.z *= dk; v.w *= dk;
            }
            *(float4*)(z_s + k * H + hq * 4) = v;
        }
        __syncthreads();
        #pragma unroll 8
        for (int k = 0; k < KT; ++k) {
            float ar[4];
            #pragma unroll
            for (int r = 0; r < 4; ++r) ar[r] = a_s[(ty * 4 + r) * 68 + k];
            float zv[CPT];
            #pragma unroll
            for (int u = 0; u < CPT; ++u) {
                int h = tx * CPT + u;
                if (H < HP && h >= H) h = 0;
                zv[u] = z_s[k * H + h];
            }
            #pragma unroll
            for (int r = 0; r < 4; ++r)
                #pragma unroll
                for (int u = 0; u < CPT; ++u)
                    acc[r][u] += ar[r] * zv[u];
        }
    }
    #pragma unroll
    for (int r = 0; r < 4; ++r) {
        int i = rt * 64 + ty * 4 + r;
        float di = dloc[i];
        #pragma unroll
        for (int u = 0; u < CPT; ++u) {
            int h = tx * CPT + u;
            if (H < HP && h >= H) continue;
            float self = SHARED ? di * ZG[(size_t)i * H + h] : ZG[(size_t)i * H + h];
            float v = di * (acc[r][u] + self) + bias[h];
            if (ACT) v = v >= 0.f ? v : 0.2f * v;
            xout[((size_t)bc * NN + i) * H + h] = v;
        }
    }
}

template<int HI, int HO>
__global__ __launch_bounds__(256) void k_smallgemm(
    const float* __restrict__ xin, const float* __restrict__ wp,
    const float* __restrict__ wn, const float* __restrict__ dinv,
    float* __restrict__ zc)
{
    constexpr int CPT = (HO >= 16) ? HO / 16 : 1;
    constexpr int XS = HI + 4;
    __shared__ float x_s[32 * XS];
    __shared__ float w_s[HI * HO];
    const int bc = blockIdx.y, jt = blockIdx.x, t = threadIdx.x;
    const int tx = t & 15, ty = t >> 4;
    const float* W = (bc & 1) ? wn : wp;
    const float* X = xin + ((size_t)bc * NN + jt * 32) * HI;
    for (int idx = t; idx < HI * HO / 4; idx += 256)
        *(float4*)(w_s + idx * 4) = *(const float4*)(W + idx * 4);
    for (int idx = t; idx < 32 * HI / 4; idx += 256) {
        int r = idx / (HI / 4), q = idx % (HI / 4);
        *(float4*)(x_s + r * XS + q * 4) = *(const float4*)(X + (size_t)r * HI + q * 4);
    }
    __syncthreads();
    float acc[2][CPT];
    #pragma unroll
    for (int r = 0; r < 2; ++r)
        #pragma unroll
        for (int u = 0; u < CPT; ++u) acc[r][u] = 0.f;
    #pragma unroll 4
    for (int p = 0; p < HI; ++p) {
        float xr[2];
        #pragma unroll
        for (int r = 0; r < 2; ++r) xr[r] = x_s[(ty * 2 + r) * XS + p];
        float wv[CPT];
        #pragma unroll
        for (int u = 0; u < CPT; ++u) {
            int h = tx * CPT + u;
            if (HO < 16 && h >= HO) h = 0;
            wv[u] = w_s[p * HO + h];
        }
        #pragma unroll
        for (int r = 0; r < 2; ++r)
            #pragma unroll
            for (int u = 0; u < CPT; ++u) acc[r][u] += xr[r] * wv[u];
    }
    const float* dloc = dinv + bc * NN;
    #pragma unroll
    for (int r = 0; r < 2; ++r) {
        int j = jt * 32 + ty * 2 + r;
        float dj = dloc[j];
        #pragma unroll
        for (int u = 0; u < CPT; ++u) {
            int h = tx * CPT + u;
            if (HO < 16 && h >= HO) continue;
            zc[((size_t)bc * NN + j) * HO + h] = dj * acc[r][u];
        }
    }
}

// ---------------- DCL head (shared by both paths) ---------------------------
__global__ __launch_bounds__(256) void k_dcl(
    const float* __restrict__ x3, const float* __restrict__ x4,
    const float* __restrict__ wc, const int* __restrict__ task,
    float* __restrict__ L)
{
    __shared__ float ps[8][32];
    __shared__ float xf[32];
    __shared__ float pr[72];
    const int bc = blockIdx.x, t = threadIdx.x;
    const float* X3 = x3 + (size_t)bc * NN * 32;
    {
        int col = t & 31, rg = t >> 5;
        float s = 0.f;
        for (int r = rg; r < NN; r += 8) s += X3[r * 32 + col];
        ps[rg][col] = s;
    }
    __syncthreads();
    if (t < 32) {
        float s = 0.f;
        #pragma unroll
        for (int g = 0; g < 8; ++g) s += ps[g][t];
        xf[t] = s * (1.0f / 512.0f);
    }
    __syncthreads();
    if (t < 72) {
        int tid = task[bc >> 1];
        const float* wr = wc + t * 48;
        float s = wr[32 + tid];
        #pragma unroll
        for (int j = 0; j < 32; ++j) s += wr[j] * xf[j];
        pr[t] = s;
    }
    __syncthreads();
    const float* X4 = x4 + (size_t)bc * 4096;
    float* Lb = L + (size_t)bc * 4096;
    #pragma unroll
    for (int rep = 0; rep < 2; ++rep) {
        int n = rep * 256 + t;
        float hi[8];
        #pragma unroll
        for (int i = 0; i < 8; ++i) hi[i] = X4[i * 512 + n];
        #pragma unroll
        for (int o = 0; o < 8; ++o) {
            float s = pr[64 + o];
            #pragma unroll
            for (int i = 0; i < 8; ++i) s += pr[o * 8 + i] * hi[i];
            Lb[o * 512 + n] = s;
        }
    }
}

// ---------------- final: out[bc][n][m] = softplus(-cc_n . cc_m) -------------
#define SCP 520
__global__ __launch_bounds__(256) void k_final(const float* __restrict__ L,
                                               float* __restrict__ out)
{
    __shared__ float scT[8 * SCP];
    const int bcid = blockIdx.y;
    const int b = bcid >> 1, c = bcid & 1;
    const int nt = blockIdx.x, t = threadIdx.x;
    const float* Lp = L + (size_t)(b * 2) * 4096;
    const float* Ln = Lp + 4096;
    for (int rep = 0; rep < 16; ++rep) {
        int e = rep * 256 + t;
        int f = c * 4096 + e;
        int n = f >> 4, k = f & 15;
        float v = (k < 8) ? Lp[n * 8 + k] : Ln[n * 8 + k - 8];
        scT[(e & 7) * SCP + (e >> 3)] = v;
    }
    __syncthreads();
    const int tx = t & 63, ty = t >> 6;
    const int n0 = nt * 32 + ty * 8;
    float cn[8][8];
    #pragma unroll
    for (int o = 0; o < 8; ++o)
        #pragma unroll
        for (int i = 0; i < 8; ++i) cn[i][o] = scT[o * SCP + n0 + i];
    float* ob = out + (size_t)bcid * NN * NN;
    #pragma unroll 2
    for (int mg = 0; mg < 8; ++mg) {
        int m = tx + mg * 64;
        float cm[8];
        #pragma unroll
        for (int o = 0; o < 8; ++o) cm[o] = scT[o * SCP + m];
        #pragma unroll
        for (int i = 0; i < 8; ++i) {
            float s = 0.f;
            #pragma unroll
            for (int o = 0; o < 8; ++o) s += cn[i][o] * cm[o];
            float r = fmaxf(-s, 0.f) + __logf(1.0f + __expf(-fabsf(s)));
            ob[(size_t)(n0 + i) * NN + m] = r;
        }
    }
}

extern "C" void kernel_launch(void* const* d_in, const int* in_sizes, int n_in,
                              void* d_out, int out_size, void* d_ws, size_t ws_size,
                              hipStream_t stream)
{
    const float* adj = (const float*)d_in[0];
    const int*  task = (const int*)d_in[1];
    const float* w1p = (const float*)d_in[2];  const float* b1p = (const float*)d_in[3];
    const float* w2p = (const float*)d_in[4];  const float* b2p = (const float*)d_in[5];
    const float* w3p = (const float*)d_in[6];  const float* b3p = (const float*)d_in[7];
    const float* w4p = (const float*)d_in[8];  const float* b4p = (const float*)d_in[9];
    const float* w1n = (const float*)d_in[10]; const float* b1n = (const float*)d_in[11];
    const float* w2n = (const float*)d_in[12]; const float* b2n = (const float*)d_in[13];
    const float* w3n = (const float*)d_in[14]; const float* b3n = (const float*)d_in[15];
    const float* w4n = (const float*)d_in[16]; const float* b4n = (const float*)d_in[17];
    const float* wc  = (const float*)d_in[18];
    (void)in_sizes; (void)n_in; (void)out_size;

    const size_t NEED = 198004736ull;
    if (ws_size >= NEED) {
        char* base = (char*)d_ws;
        float*          dinv = (float*)(base + 0);
        unsigned short* anh  = (unsigned short*)(base + 262144);
        unsigned short* anl  = (unsigned short*)(base + 67371008);
        unsigned short* zt1h = (unsigned short*)(base + 134479872);
        unsigned short* zt1l = (unsigned short*)(base + 134742016);
        unsigned short* wt2h = (unsigned short*)(base + 135004160);
        unsigned short* wt2l = (unsigned short*)(base + 135036928);
        unsigned short* wt3h = (unsigned short*)(base + 135069696);
        unsigned short* wt3l = (unsigned short*)(base + 135077888);
        unsigned short* wt4h = (unsigned short*)(base + 135086080);
        unsigned short* wt4l = (unsigned short*)(base + 135088128);
        unsigned short* x1h  = (unsigned short*)(base + 135090176);
        unsigned short* x1l  = (unsigned short*)(base + 151867392);
        unsigned short* zt2h = (unsigned short*)(base + 168644608);
        unsigned short* zt2l = (unsigned short*)(base + 177033216);
        float*          x3f  = (float*)(base + 185421824);
        float*          x4f  = (float*)(base + 193810432);
        float*          L    = (float*)(base + 195907584);
        // aliases (lifetimes disjoint across kernel boundaries)
        unsigned short* x2h = x1h,  *x2l = x1l;
        unsigned short* x3h = x1h,  *x3l = x1l;
        unsigned short* zt3h = zt2h, *zt3l = zt2l;
        unsigned short* zt4h = zt2h, *zt4l = zt2l;

        k_rowsum<<<dim3(NBC * NN / 4), 256, 0, stream>>>(adj, dinv);
        k_convert<<<dim3(16384), 256, 0, stream>>>(adj, dinv, anh, anl);
        WJobs jobs;
        jobs.j[0] = {w1p, zt1h,          zt1l,          512, 128, 128};
        jobs.j[1] = {w1n, zt1h + 65536,  zt1l + 65536,  512, 128, 128};
        jobs.j[2] = {w2p, wt2h,          wt2l,          128,  64,  64};
        jobs.j[3] = {w2n, wt2h + 8192,   wt2l + 8192,   128,  64,  64};
        jobs.j[4] = {w3p, wt3h,          wt3l,           64,  32,  32};
        jobs.j[5] = {w3n, wt3h + 2048,   wt3l + 2048,    64,  32,  32};
        jobs.j[6] = {w4p, wt4h,          wt4l,           32,   8,  16};
        jobs.j[7] = {w4n, wt4h + 512,    wt4l + 512,     32,   8,  16};
        k_wprep<<<dim3(256, 8), 256, 0, stream>>>(jobs);

        k_mfma<128, 128, true,  true,  true,  3><<<dim3(8, NBC), 256, 0, stream>>>(
            anh, anl, zt1h, zt1l, b1p, b1n, nullptr, x1h, x1l);
        k_zgemm<128, 64><<<dim3(4, NBC), 256, 0, stream>>>(wt2h, wt2l, x1h, x1l, zt2h, zt2l);
        k_mfma<64, 64, false, true,  true,  4><<<dim3(8, NBC), 256, 0, stream>>>(
            anh, anl, zt2h, zt2l, b2p, b2n, nullptr, x2h, x2l);
        k_zgemm<64, 32><<<dim3(4, NBC), 256, 0, stream>>>(wt3h, wt3l, x2h, x2l, zt3h, zt3l);
        k_mfma<32, 32, false, true,  true,  4><<<dim3(8, NBC), 256, 0, stream>>>(
            anh, anl, zt3h, zt3l, b3p, b3n, x3f, x3h, x3l);
        k_zgemm<32, 16><<<dim3(4, NBC), 256, 0, stream>>>(wt4h, wt4l, x3h, x3l, zt4h, zt4l);
        k_mfma<16, 8, false, false, false, 4><<<dim3(8, NBC), 256, 0, stream>>>(
            anh, anl, zt4h, zt4l, b4p, b4n, x4f, nullptr, nullptr);
        k_dcl<<<dim3(NBC), 256, 0, stream>>>(x3f, x4f, wc, task, L);
        k_final<<<dim3(16, NBC), 256, 0, stream>>>(L, (float*)d_out);
    } else {
        // -------- fallback: proven R2 fp32 path (needs ~63 MB) --------
        float* ws   = (float*)d_ws;
        float* dinv = ws;
        float* XA   = ws + 65536;
        float* X3   = XA + 8388608;
        float* X4   = X3 + 2097152;
        float* L    = X4 + 524288;
        float* ZC   = L  + 524288;
        k_rowsum<<<dim3(NBC * NN / 4), 256, 0, stream>>>(adj, dinv);
        k_biggemm<128,128,true ,true ><<<dim3(8,128), 256, 0, stream>>>(adj, nullptr, w1p, w1n, b1p, b1n, dinv, XA);
        k_smallgemm<128,64><<<dim3(16,128), 256, 0, stream>>>(XA, w2p, w2n, dinv, ZC);
        k_biggemm<64,64,false,true ><<<dim3(8,128), 256, 0, stream>>>(adj, ZC, nullptr, nullptr, b2p, b2n, dinv, XA);
        k_smallgemm<64,32><<<dim3(16,128), 256, 0, stream>>>(XA, w3p, w3n, dinv, ZC);
        k_biggemm<32,32,false,true ><<<dim3(8,128), 256, 0, stream>>>(adj, ZC, nullptr, nullptr, b3p, b3n, dinv, X3);
        k_smallgemm<32,8><<<dim3(16,128), 256, 0, stream>>>(X3, w4p, w4n, dinv, ZC);
        k_biggemm<8,16,false,false><<<dim3(8,128), 256, 0, stream>>>(adj, ZC, nullptr, nullptr, b4p, b4n, dinv, X4);
        k_dcl<<<dim3(128), 256, 0, stream>>>(X3, X4, wc, task, L);
        k_final<<<dim3(16,128), 256, 0, stream>>>(L, (float*)d_out);
    }
}

// Round 5
// 559.894 us; speedup vs baseline: 1.0029x; 1.0029x over previous
//
#include <hip/hip_runtime.h>
#include <math.h>

#define NN 512
#define NBC 128   // B*2

typedef __attribute__((ext_vector_type(8))) __bf16 v8bf;
typedef __attribute__((ext_vector_type(4))) float v4f;

// round-to-nearest-even bf16 split: v = hi + lo (+O(2^-17) rel)
__device__ __forceinline__ void bsplit(float v, unsigned short& h, unsigned short& l) {
    unsigned u  = __builtin_bit_cast(unsigned, v);
    unsigned hb = (u + 0x7fffu + ((u >> 16) & 1u)) & 0xffff0000u;
    float hf    = __builtin_bit_cast(float, hb);
    h = (unsigned short)(hb >> 16);
    float lof   = v - hf;
    unsigned ul = __builtin_bit_cast(unsigned, lof);
    l = (unsigned short)((ul + 0x7fffu + ((ul >> 16) & 1u)) >> 16);
}

// ---------------- degree: dinv[bc][i] = rsqrt(1 + sum_j adj[bc][i][j]) -----
__global__ __launch_bounds__(256) void k_rowsum(const float* __restrict__ adj,
                                                float* __restrict__ dinv) {
    int wave = blockIdx.x * 4 + (threadIdx.x >> 6);
    int lane = threadIdx.x & 63;
    const float4* row = (const float4*)(adj + (size_t)wave * NN);
    float4 v0 = row[lane], v1 = row[lane + 64];
    float s = v0.x + v0.y + v0.z + v0.w + v1.x + v1.y + v1.z + v1.w;
    #pragma unroll
    for (int off = 32; off; off >>= 1) s += __shfl_down(s, off, 64);
    if (lane == 0) dinv[wave] = rsqrtf(1.0f + s);
}

// ---------------- weight prep: dst[h][p] = split(w[p][h]) (zero-pad h>=HO) --
struct WJob  { const float* w; unsigned short* dh; unsigned short* dl; int HI; int HO; int HOP; };
struct WJobs { WJob j[8]; };
__global__ __launch_bounds__(256) void k_wprep(WJobs jobs) {
    WJob jb = jobs.j[blockIdx.y];
    int idx = blockIdx.x * 256 + threadIdx.x;
    if (idx >= jb.HOP * jb.HI) return;
    int h = idx / jb.HI, p = idx % jb.HI;
    float v = (h < jb.HO) ? jb.w[p * jb.HO + h] : 0.f;
    unsigned short hh, ll; bsplit(v, hh, ll);
    jb.dh[idx] = hh; jb.dl[idx] = ll;
}

// ---------------- MFMA layer: X = act(D(adj+I)D @ Z + b), fold-D fused ------
// An is NEVER materialized: each block reg-stages raw adj fp32, applies
// di*dj*(a+I) + bsplit on the fly (bit-identical to the old k_convert),
// ds_writes hi/lo tiles, then MFMA-reads fragments.  adj (134 MB) fits L3,
// so after k_rowsum all A-reads are L3 hits.  Z (bf16 hi/lo, [s][n][k]
// k-contig) is reg-staged cooperatively into LDS too.  Plain loads -> the
// compiler inserts precise counted waitcnts (no manual vmcnt); raw s_barrier
// (1 per K-step) avoids the vmcnt(0) drain so prefetches stay in flight.
// A prefetch depth 3, Z depth 2, 2 LDS buffers, padded stride 40 (2-way
// bank aliasing = free, 16B-aligned b128).
// 3-term split: Ah@Zh + Ah@Zl + Al@Zh (order preserved -> bit-identical).
template<int BN, int OUTW, bool SHAREDZ, bool ACT, bool WBF, int MINW>
__global__ __launch_bounds__(256, MINW) void k_mfma(
    const float* __restrict__ adj, const float* __restrict__ dinv,
    const unsigned short* __restrict__ zh_,  const unsigned short* __restrict__ zl_,
    const float* __restrict__ bp, const float* __restrict__ bn,
    float* __restrict__ xf, unsigned short* __restrict__ xh, unsigned short* __restrict__ xl)
{
    constexpr int WC  = (BN >= 32) ? 2 : 1;     // col-split waves
    constexpr int WR  = 4 / WC;                 // row-split waves
    constexpr int RF  = 64 / (WR * 16);         // 16-row frags per wave
    constexpr int C   = (BN / WC) / 16;         // 16-col frags per wave
    constexpr int AS  = 40;                     // LDS row stride (shorts)
    constexpr int APL = 64 * AS;                // A plane (2560 shorts)
    constexpr int ABUF = 2 * APL;               // A hi+lo per buffer
    constexpr int ZPL = BN * AS;                // Z plane
    constexpr int ZBUF = 2 * ZPL;
    constexpr int ZCH = (BN == 128) ? 2 : 1;    // 8-short chunks per thread
    constexpr int ZTHREADS = (BN >= 64) ? 256 : BN * 4;
    __shared__ __align__(16) unsigned short sm[2 * ABUF + 2 * ZBUF];
    __shared__ float dls[512];

    const int bc = blockIdx.y, rb = blockIdx.x;
    const int t = threadIdx.x, w = t >> 6, lane = t & 63;
    const int m0 = lane & 15, quad = lane >> 4;
    const int wr = w / WC, wcc = w % WC;
    const int s = SHAREDZ ? (bc & 1) : bc;

    // A staging map: thread = (row, 8-col group)
    const int arow = t >> 2, c8 = t & 3;
    const int gcol0 = c8 * 8;
    const int growi = rb * 64 + arow;           // global row (diagonal test)
    const float* gA = adj + ((size_t)bc * NN + growi) * NN + gcol0;
    const float di = dinv[bc * NN + growi];
    const bool zact = (ZTHREADS == 256) || (t < ZTHREADS);

    float4 aR[3][2];
    uint4  zRh[2][ZCH], zRl[2][ZCH];

    auto LOADA = [&](int kb, int slot) {
        aR[slot][0] = *(const float4*)(gA + (size_t)kb * 32);
        aR[slot][1] = *(const float4*)(gA + (size_t)kb * 32 + 4);
    };
    auto LOADZ = [&](int kb, int slot) {
        if (zact) {
            #pragma unroll
            for (int q = 0; q < ZCH; ++q) {
                int ci = (ZCH == 2) ? (t * 2 + q) : t;
                int zn = ci >> 2, zk = (ci & 3) * 8;
                size_t go = ((size_t)s * BN + zn) * NN + (size_t)kb * 32 + zk;
                zRh[slot][q] = *(const uint4*)(zh_ + go);
                zRl[slot][q] = *(const uint4*)(zl_ + go);
            }
        }
    };
    auto WRITEA = [&](int kb, int buf) {
        // identical math to the old k_convert: v = di * dj * (a + I)
        const int slot = kb % 3;
        const float4 d0 = *(const float4*)(&dls[kb * 32 + gcol0]);
        const float4 d1 = *(const float4*)(&dls[kb * 32 + gcol0 + 4]);
        float av[8] = { aR[slot][0].x, aR[slot][0].y, aR[slot][0].z, aR[slot][0].w,
                        aR[slot][1].x, aR[slot][1].y, aR[slot][1].z, aR[slot][1].w };
        float dj[8] = { d0.x, d0.y, d0.z, d0.w, d1.x, d1.y, d1.z, d1.w };
        unsigned pw[4], qw[4];
        const int jb0 = kb * 32 + gcol0;
        #pragma unroll
        for (int q = 0; q < 4; ++q) {
            unsigned short h0, l0, h1, l1;
            float u0 = di * dj[2*q]     * (av[2*q]     + ((jb0 + 2*q)     == growi ? 1.f : 0.f));
            float u1 = di * dj[2*q + 1] * (av[2*q + 1] + ((jb0 + 2*q + 1) == growi ? 1.f : 0.f));
            bsplit(u0, h0, l0); bsplit(u1, h1, l1);
            pw[q] = (unsigned)h0 | ((unsigned)h1 << 16);
            qw[q] = (unsigned)l0 | ((unsigned)l1 << 16);
        }
        uint4 ph; ph.x = pw[0]; ph.y = pw[1]; ph.z = pw[2]; ph.w = pw[3];
        uint4 pl; pl.x = qw[0]; pl.y = qw[1]; pl.z = qw[2]; pl.w = qw[3];
        *(uint4*)(&sm[buf * ABUF + arow * AS + gcol0])       = ph;
        *(uint4*)(&sm[buf * ABUF + APL + arow * AS + gcol0]) = pl;
    };
    auto WRITEZ = [&](int slot, int buf) {
        if (zact) {
            #pragma unroll
            for (int q = 0; q < ZCH; ++q) {
                int ci = (ZCH == 2) ? (t * 2 + q) : t;
                int zn = ci >> 2, zk = (ci & 3) * 8;
                *(uint4*)(&sm[2 * ABUF + buf * ZBUF + zn * AS + zk])       = zRh[slot][q];
                *(uint4*)(&sm[2 * ABUF + buf * ZBUF + ZPL + zn * AS + zk]) = zRl[slot][q];
            }
        }
    };

    v4f acc[RF][C];
    #pragma unroll
    for (int r = 0; r < RF; ++r)
        #pragma unroll
        for (int c = 0; c < C; ++c) acc[r][c] = (v4f){0.f, 0.f, 0.f, 0.f};

    // -------- prologue --------
    if (t < 128) *(float4*)(&dls[t * 4]) = *(const float4*)(dinv + bc * NN + t * 4);
    LOADA(0, 0); LOADA(1, 1); LOADA(2, 2);
    LOADZ(0, 0); LOADZ(1, 1);
    __syncthreads();                            // dls visible (one-time drain)
    WRITEA(0, 0); WRITEZ(0, 0);
    asm volatile("" ::: "memory");
    __builtin_amdgcn_s_barrier();               // buf0 ready
    asm volatile("" ::: "memory");

    // -------- main loop: 1 barrier per K-step --------
    #pragma unroll
    for (int kb = 0; kb < 16; ++kb) {
        const int cur = kb & 1;
        if (kb + 3 < 16) LOADA(kb + 3, (kb + 3) % 3);
        if (kb + 2 < 16) LOADZ(kb + 2, cur);    // slot cur: Z(kb) already in LDS

        const unsigned short* ab = sm + (size_t)(cur * ABUF);
        const unsigned short* zb = sm + (size_t)(2 * ABUF + cur * ZBUF);
        v8bf zfh[C], zfl[C];
        #pragma unroll
        for (int c = 0; c < C; ++c) {
            int n = wcc * (BN / WC) + c * 16 + m0;
            zfh[c] = *(const v8bf*)(zb + n * AS + quad * 8);
            zfl[c] = *(const v8bf*)(zb + ZPL + n * AS + quad * 8);
        }
        #pragma unroll
        for (int r = 0; r < RF; ++r) {
            int rho = wr * (RF * 16) + r * 16 + m0;
            v8bf ah = *(const v8bf*)(ab + rho * AS + quad * 8);
            v8bf al = *(const v8bf*)(ab + APL + rho * AS + quad * 8);
            #pragma unroll
            for (int c = 0; c < C; ++c) {
                acc[r][c] = __builtin_amdgcn_mfma_f32_16x16x32_bf16(ah, zfh[c], acc[r][c], 0, 0, 0);
                acc[r][c] = __builtin_amdgcn_mfma_f32_16x16x32_bf16(ah, zfl[c], acc[r][c], 0, 0, 0);
                acc[r][c] = __builtin_amdgcn_mfma_f32_16x16x32_bf16(al, zfh[c], acc[r][c], 0, 0, 0);
            }
        }
        if (kb + 1 < 16) {
            WRITEA(kb + 1, cur ^ 1);            // buf[cur^1] last read 2 barriers ago
            WRITEZ(cur ^ 1, cur ^ 1);           // Z(kb+1) is in slot (kb+1)&1 = cur^1
            asm volatile("" ::: "memory");
            __builtin_amdgcn_s_barrier();       // writes visible for next iter's reads
            asm volatile("" ::: "memory");
        }
    }

    const float* bias = (bc & 1) ? bn : bp;
    #pragma unroll
    for (int r = 0; r < RF; ++r)
        #pragma unroll
        for (int c = 0; c < C; ++c) {
            int col = wcc * (BN / WC) + c * 16 + m0;
            if (OUTW < BN && col >= OUTW) continue;
            float bv = bias[col];
            #pragma unroll
            for (int reg = 0; reg < 4; ++reg) {
                int row = rb * 64 + wr * (RF * 16) + r * 16 + quad * 4 + reg;
                float v = acc[r][c][reg] + bv;
                if (ACT) v = v >= 0.f ? v : 0.2f * v;
                size_t oi = ((size_t)bc * NN + row) * OUTW + col;
                if (xf) xf[oi] = v;
                if (WBF) {
                    unsigned short hh, ll; bsplit(v, hh, ll);
                    xh[oi] = hh; xl[oi] = ll;
                }
            }
        }
}

// ---------------- MFMA Z-gemm: Zt[h][j] = sum_p W[p][h] X[j][p] -------------
// A = Wt [s][h][p] (p contig), B = X [bc][j][p] (p contig), out transposed.
template<int HI, int HOP>
__global__ __launch_bounds__(256) void k_zgemm(
    const unsigned short* __restrict__ wth, const unsigned short* __restrict__ wtl,
    const unsigned short* __restrict__ xh_, const unsigned short* __restrict__ xl_,
    unsigned short* __restrict__ zh_, unsigned short* __restrict__ zl_)
{
    constexpr int MT = HOP / 16, JW = 4 / MT, NT = 8 / JW;
    const int bc = blockIdx.y, jb = blockIdx.x;
    const int t = threadIdx.x, w = t >> 6, lane = t & 63;
    const int m0 = lane & 15, quad = lane >> 4;
    const int mt = w % MT, jseg = w / MT;
    const int n0 = jb * 128 + jseg * (128 / JW);
    const int s = bc & 1;
    const unsigned short* pw_h = wth + ((size_t)s * HOP + mt * 16 + m0) * HI + quad * 8;
    const unsigned short* pw_l = wtl + ((size_t)s * HOP + mt * 16 + m0) * HI + quad * 8;
    const unsigned short* px_h = xh_ + ((size_t)bc * NN + n0 + m0) * HI + quad * 8;
    const unsigned short* px_l = xl_ + ((size_t)bc * NN + n0 + m0) * HI + quad * 8;
    v4f acc[NT];
    #pragma unroll
    for (int c = 0; c < NT; ++c) acc[c] = (v4f){0.f, 0.f, 0.f, 0.f};
    #pragma unroll
    for (int ks = 0; ks < HI / 32; ++ks) {
        const int ko = ks * 32;
        v8bf awh = *(const v8bf*)(pw_h + ko);
        v8bf awl = *(const v8bf*)(pw_l + ko);
        #pragma unroll
        for (int c = 0; c < NT; ++c) {
            v8bf bxh = *(const v8bf*)(px_h + (size_t)(c * 16) * HI + ko);
            v8bf bxl = *(const v8bf*)(px_l + (size_t)(c * 16) * HI + ko);
            acc[c] = __builtin_amdgcn_mfma_f32_16x16x32_bf16(awh, bxh, acc[c], 0, 0, 0);
            acc[c] = __builtin_amdgcn_mfma_f32_16x16x32_bf16(awh, bxl, acc[c], 0, 0, 0);
            acc[c] = __builtin_amdgcn_mfma_f32_16x16x32_bf16(awl, bxh, acc[c], 0, 0, 0);
        }
    }
    #pragma unroll
    for (int c = 0; c < NT; ++c) {
        int j = n0 + c * 16 + m0;
        #pragma unroll
        for (int reg = 0; reg < 4; ++reg) {
            int h = mt * 16 + quad * 4 + reg;
            unsigned short hh, ll; bsplit(acc[c][reg], hh, ll);
            size_t oi = ((size_t)bc * HOP + h) * NN + j;
            zh_[oi] = hh; zl_[oi] = ll;
        }
    }
}

// ================= FALLBACK (R2 proven path, fp32 vector) ===================
template<int H, int HP, bool SHARED, bool ACT>
__global__ __launch_bounds__(256) void k_biggemm(
    const float* __restrict__ adj, const float* __restrict__ zcg,
    const float* __restrict__ wp, const float* __restrict__ wn,
    const float* __restrict__ bp, const float* __restrict__ bn,
    const float* __restrict__ dinv, float* __restrict__ xout)
{
    constexpr int CPT = HP / 16;
    constexpr int KT = 64;
    __shared__ float a_s[64 * 68];
    __shared__ float z_s[KT * H];
    const int bc = blockIdx.y;
    const int rt = blockIdx.x;
    const int t  = threadIdx.x;
    const int tx = t & 15, ty = t >> 4;
    const float* A    = adj + (size_t)bc * NN * NN + (size_t)rt * 64 * NN;
    const float* dloc = dinv + bc * NN;
    const float* ZG   = SHARED ? ((bc & 1) ? wn : wp) : (zcg + (size_t)bc * NN * H);
    const float* bias = (bc & 1) ? bn : bp;
    float acc[4][CPT];
    #pragma unroll
    for (int r = 0; r < 4; ++r)
        #pragma unroll
        for (int u = 0; u < CPT; ++u) acc[r][u] = 0.f;
    for (int kb = 0; kb < NN; kb += KT) {
        __syncthreads();
        #pragma unroll
        for (int l = 0; l < 4; ++l) {
            int idx = t + l * 256;
            int r = idx >> 4, q = idx & 15;
            float4 v = *(const float4*)(A + (size_t)r * NN + kb + q * 4);
            *(float4*)(a_s + r * 68 + q * 4) = v;
        }
        constexpr int NZ4 = KT * H / 4;
        for (int idx = t; idx < NZ4; idx += 256) {
            int k = idx / (H / 4), hq = idx % (H / 4);
            float4 v = *(const float4*)(ZG + (size_t)(kb + k) * H + hq * 4);
            if (SHARED) {
                float dk = dloc[kb + k];
                v.x *= dk; v.y *= dk; v.z *= dk; v.w *= dk;
            }
            *(float4*)(z_s + k * H + hq * 4) = v;
        }
        __syncthreads();
        #pragma unroll 8
        for (int k = 0; k < KT; ++k) {
            float ar[4];
            #pragma unroll
            for (int r = 0; r < 4; ++r) ar[r] = a_s[(ty * 4 + r) * 68 + k];
            float zv[CPT];
            #pragma unroll
            for (int u = 0; u < CPT; ++u) {
                int h = tx * CPT + u;
                if (H < HP && h >= H) h = 0;
                zv[u] = z_s[k * H + h];
            }
            #pragma unroll
            for (int r = 0; r < 4; ++r)
                #pragma unroll
                for (int u = 0; u < CPT; ++u)
                    acc[r][u] += ar[r] * zv[u];
        }
    }
    #pragma unroll
    for (int r = 0; r < 4; ++r) {
        int i = rt * 64 + ty * 4 + r;
        float di = dloc[i];
        #pragma unroll
        for (int u = 0; u < CPT; ++u) {
            int h = tx * CPT + u;
            if (H < HP && h >= H) continue;
            float self = SHARED ? di * ZG[(size_t)i * H + h] : ZG[(size_t)i * H + h];
            float v = di * (acc[r][u] + self) + bias[h];
            if (ACT) v = v >= 0.f ? v : 0.2f * v;
            xout[((size_t)bc * NN + i) * H + h] = v;
        }
    }
}

template<int HI, int HO>
__global__ __launch_bounds__(256) void k_smallgemm(
    const float* __restrict__ xin, const float* __restrict__ wp,
    const float* __restrict__ wn, const float* __restrict__ dinv,
    float* __restrict__ zc)
{
    constexpr int CPT = (HO >= 16) ? HO / 16 : 1;
    constexpr int XS = HI + 4;
    __shared__ float x_s[32 * XS];
    __shared__ float w_s[HI * HO];
    const int bc = blockIdx.y, jt = blockIdx.x, t = threadIdx.x;
    const int tx = t & 15, ty = t >> 4;
    const float* W = (bc & 1) ? wn : wp;
    const float* X = xin + ((size_t)bc * NN + jt * 32) * HI;
    for (int idx = t; idx < HI * HO / 4; idx += 256)
        *(float4*)(w_s + idx * 4) = *(const float4*)(W + idx * 4);
    for (int idx = t; idx < 32 * HI / 4; idx += 256) {
        int r = idx / (HI / 4), q = idx % (HI / 4);
        *(float4*)(x_s + r * XS + q * 4) = *(const float4*)(X + (size_t)r * HI + q * 4);
    }
    __syncthreads();
    float acc[2][CPT];
    #pragma unroll
    for (int r = 0; r < 2; ++r)
        #pragma unroll
        for (int u = 0; u < CPT; ++u) acc[r][u] = 0.f;
    #pragma unroll 4
    for (int p = 0; p < HI; ++p) {
        float xr[2];
        #pragma unroll
        for (int r = 0; r < 2; ++r) xr[r] = x_s[(ty * 2 + r) * XS + p];
        float wv[CPT];
        #pragma unroll
        for (int u = 0; u < CPT; ++u) {
            int h = tx * CPT + u;
            if (HO < 16 && h >= HO) h = 0;
            wv[u] = w_s[p * HO + h];
        }
        #pragma unroll
        for (int r = 0; r < 2; ++r)
            #pragma unroll
            for (int u = 0; u < CPT; ++u) acc[r][u] += xr[r] * wv[u];
    }
    const float* dloc = dinv + bc * NN;
    #pragma unroll
    for (int r = 0; r < 2; ++r) {
        int j = jt * 32 + ty * 2 + r;
        float dj = dloc[j];
        #pragma unroll
        for (int u = 0; u < CPT; ++u) {
            int h = tx * CPT + u;
            if (HO < 16 && h >= HO) continue;
            zc[((size_t)bc * NN + j) * HO + h] = dj * acc[r][u];
        }
    }
}

// ---------------- DCL head (shared by both paths) ---------------------------
__global__ __launch_bounds__(256) void k_dcl(
    const float* __restrict__ x3, const float* __restrict__ x4,
    const float* __restrict__ wc, const int* __restrict__ task,
    float* __restrict__ L)
{
    __shared__ float ps[8][32];
    __shared__ float xf[32];
    __shared__ float pr[72];
    const int bc = blockIdx.x, t = threadIdx.x;
    const float* X3 = x3 + (size_t)bc * NN * 32;
    {
        int col = t & 31, rg = t >> 5;
        float s = 0.f;
        for (int r = rg; r < NN; r += 8) s += X3[r * 32 + col];
        ps[rg][col] = s;
    }
    __syncthreads();
    if (t < 32) {
        float s = 0.f;
        #pragma unroll
        for (int g = 0; g < 8; ++g) s += ps[g][t];
        xf[t] = s * (1.0f / 512.0f);
    }
    __syncthreads();
    if (t < 72) {
        int tid = task[bc >> 1];
        const float* wr = wc + t * 48;
        float s = wr[32 + tid];
        #pragma unroll
        for (int j = 0; j < 32; ++j) s += wr[j] * xf[j];
        pr[t] = s;
    }
    __syncthreads();
    const float* X4 = x4 + (size_t)bc * 4096;
    float* Lb = L + (size_t)bc * 4096;
    #pragma unroll
    for (int rep = 0; rep < 2; ++rep) {
        int n = rep * 256 + t;
        float hi[8];
        #pragma unroll
        for (int i = 0; i < 8; ++i) hi[i] = X4[i * 512 + n];
        #pragma unroll
        for (int o = 0; o < 8; ++o) {
            float s = pr[64 + o];
            #pragma unroll
            for (int i = 0; i < 8; ++i) s += pr[o * 8 + i] * hi[i];
            Lb[o * 512 + n] = s;
        }
    }
}

// ---------------- final: out[bc][n][m] = softplus(-cc_n . cc_m) -------------
#define SCP 520
__global__ __launch_bounds__(256) void k_final(const float* __restrict__ L,
                                               float* __restrict__ out)
{
    __shared__ float scT[8 * SCP];
    const int bcid = blockIdx.y;
    const int b = bcid >> 1, c = bcid & 1;
    const int nt = blockIdx.x, t = threadIdx.x;
    const float* Lp = L + (size_t)(b * 2) * 4096;
    const float* Ln = Lp + 4096;
    for (int rep = 0; rep < 16; ++rep) {
        int e = rep * 256 + t;
        int f = c * 4096 + e;
        int n = f >> 4, k = f & 15;
        float v = (k < 8) ? Lp[n * 8 + k] : Ln[n * 8 + k - 8];
        scT[(e & 7) * SCP + (e >> 3)] = v;
    }
    __syncthreads();
    const int tx = t & 63, ty = t >> 6;
    const int n0 = nt * 32 + ty * 8;
    float cn[8][8];
    #pragma unroll
    for (int o = 0; o < 8; ++o)
        #pragma unroll
        for (int i = 0; i < 8; ++i) cn[i][o] = scT[o * SCP + n0 + i];
    float* ob = out + (size_t)bcid * NN * NN;
    #pragma unroll 2
    for (int mg = 0; mg < 8; ++mg) {
        int m = tx + mg * 64;
        float cm[8];
        #pragma unroll
        for (int o = 0; o < 8; ++o) cm[o] = scT[o * SCP + m];
        #pragma unroll
        for (int i = 0; i < 8; ++i) {
            float s = 0.f;
            #pragma unroll
            for (int o = 0; o < 8; ++o) s += cn[i][o] * cm[o];
            float r = fmaxf(-s, 0.f) + __logf(1.0f + __expf(-fabsf(s)));
            ob[(size_t)(n0 + i) * NN + m] = r;
        }
    }
}

extern "C" void kernel_launch(void* const* d_in, const int* in_sizes, int n_in,
                              void* d_out, int out_size, void* d_ws, size_t ws_size,
                              hipStream_t stream)
{
    const float* adj = (const float*)d_in[0];
    const int*  task = (const int*)d_in[1];
    const float* w1p = (const float*)d_in[2];  const float* b1p = (const float*)d_in[3];
    const float* w2p = (const float*)d_in[4];  const float* b2p = (const float*)d_in[5];
    const float* w3p = (const float*)d_in[6];  const float* b3p = (const float*)d_in[7];
    const float* w4p = (const float*)d_in[8];  const float* b4p = (const float*)d_in[9];
    const float* w1n = (const float*)d_in[10]; const float* b1n = (const float*)d_in[11];
    const float* w2n = (const float*)d_in[12]; const float* b2n = (const float*)d_in[13];
    const float* w3n = (const float*)d_in[14]; const float* b3n = (const float*)d_in[15];
    const float* w4n = (const float*)d_in[16]; const float* b4n = (const float*)d_in[17];
    const float* wc  = (const float*)d_in[18];
    (void)in_sizes; (void)n_in; (void)out_size;

    const size_t NEED = 63787008ull;
    if (ws_size >= NEED) {
        char* base = (char*)d_ws;
        float*          dinv = (float*)(base + 0);
        unsigned short* zt1h = (unsigned short*)(base + 262144);
        unsigned short* zt1l = (unsigned short*)(base + 524288);
        unsigned short* wt2h = (unsigned short*)(base + 786432);
        unsigned short* wt2l = (unsigned short*)(base + 819200);
        unsigned short* wt3h = (unsigned short*)(base + 851968);
        unsigned short* wt3l = (unsigned short*)(base + 860160);
        unsigned short* wt4h = (unsigned short*)(base + 868352);
        unsigned short* wt4l = (unsigned short*)(base + 870400);
        unsigned short* x1h  = (unsigned short*)(base + 872448);
        unsigned short* x1l  = (unsigned short*)(base + 17649664);
        unsigned short* zt2h = (unsigned short*)(base + 34426880);
        unsigned short* zt2l = (unsigned short*)(base + 42815488);
        float*          x3f  = (float*)(base + 51204096);
        float*          x4f  = (float*)(base + 59592704);
        float*          L    = (float*)(base + 61689856);
        // aliases (lifetimes disjoint across kernel boundaries)
        unsigned short* x2h = x1h,  *x2l = x1l;
        unsigned short* x3h = x1h,  *x3l = x1l;
        unsigned short* zt3h = zt2h, *zt3l = zt2l;
        unsigned short* zt4h = zt2h, *zt4l = zt2l;

        k_rowsum<<<dim3(NBC * NN / 4), 256, 0, stream>>>(adj, dinv);
        WJobs jobs;
        jobs.j[0] = {w1p, zt1h,          zt1l,          512, 128, 128};
        jobs.j[1] = {w1n, zt1h + 65536,  zt1l + 65536,  512, 128, 128};
        jobs.j[2] = {w2p, wt2h,          wt2l,          128,  64,  64};
        jobs.j[3] = {w2n, wt2h + 8192,   wt2l + 8192,   128,  64,  64};
        jobs.j[4] = {w3p, wt3h,          wt3l,           64,  32,  32};
        jobs.j[5] = {w3n, wt3h + 2048,   wt3l + 2048,    64,  32,  32};
        jobs.j[6] = {w4p, wt4h,          wt4l,           32,   8,  16};
        jobs.j[7] = {w4n, wt4h + 512,    wt4l + 512,     32,   8,  16};
        k_wprep<<<dim3(256, 8), 256, 0, stream>>>(jobs);

        k_mfma<128, 128, true,  true,  true,  2><<<dim3(8, NBC), 256, 0, stream>>>(
            adj, dinv, zt1h, zt1l, b1p, b1n, nullptr, x1h, x1l);
        k_zgemm<128, 64><<<dim3(4, NBC), 256, 0, stream>>>(wt2h, wt2l, x1h, x1l, zt2h, zt2l);
        k_mfma<64, 64, false, true,  true,  3><<<dim3(8, NBC), 256, 0, stream>>>(
            adj, dinv, zt2h, zt2l, b2p, b2n, nullptr, x2h, x2l);
        k_zgemm<64, 32><<<dim3(4, NBC), 256, 0, stream>>>(wt3h, wt3l, x2h, x2l, zt3h, zt3l);
        k_mfma<32, 32, false, true,  true,  4><<<dim3(8, NBC), 256, 0, stream>>>(
            adj, dinv, zt3h, zt3l, b3p, b3n, x3f, x3h, x3l);
        k_zgemm<32, 16><<<dim3(4, NBC), 256, 0, stream>>>(wt4h, wt4l, x3h, x3l, zt4h, zt4l);
        k_mfma<16, 8, false, false, false, 4><<<dim3(8, NBC), 256, 0, stream>>>(
            adj, dinv, zt4h, zt4l, b4p, b4n, x4f, nullptr, nullptr);
        k_dcl<<<dim3(NBC), 256, 0, stream>>>(x3f, x4f, wc, task, L);
        k_final<<<dim3(16, NBC), 256, 0, stream>>>(L, (float*)d_out);
    } else {
        // -------- fallback: proven R2 fp32 path (needs ~63 MB) --------
        float* ws   = (float*)d_ws;
        float* dinv = ws;
        float* XA   = ws + 65536;
        float* X3   = XA + 8388608;
        float* X4   = X3 + 2097152;
        float* L    = X4 + 524288;
        float* ZC   = L  + 524288;
        k_rowsum<<<dim3(NBC * NN / 4), 256, 0, stream>>>(adj, dinv);
        k_biggemm<128,128,true ,true ><<<dim3(8,128), 256, 0, stream>>>(adj, nullptr, w1p, w1n, b1p, b1n, dinv, XA);
        k_smallgemm<128,64><<<dim3(16,128), 256, 0, stream>>>(XA, w2p, w2n, dinv, ZC);
        k_biggemm<64,64,false,true ><<<dim3(8,128), 256, 0, stream>>>(adj, ZC, nullptr, nullptr, b2p, b2n, dinv, XA);
        k_smallgemm<64,32><<<dim3(16,128), 256, 0, stream>>>(XA, w3p, w3n, dinv, ZC);
        k_biggemm<32,32,false,true ><<<dim3(8,128), 256, 0, stream>>>(adj, ZC, nullptr, nullptr, b3p, b3n, dinv, X3);
        k_smallgemm<32,8><<<dim3(16,128), 256, 0, stream>>>(X3, w4p, w4n, dinv, ZC);
        k_biggemm<8,16,false,false><<<dim3(8,128), 256, 0, stream>>>(adj, ZC, nullptr, nullptr, b4p, b4n, dinv, X4);
        k_dcl<<<dim3(128), 256, 0, stream>>>(X3, X4, wc, task, L);
        k_final<<<dim3(16,128), 256, 0, stream>>>(L, (float*)d_out);
    }
}

// Round 6
// 546.906 us; speedup vs baseline: 1.0267x; 1.0237x over previous
//
#include <hip/hip_runtime.h>
#include <math.h>

#define NN 512
#define NBC 128   // B*2

typedef __attribute__((ext_vector_type(8))) __bf16 v8bf;
typedef __attribute__((ext_vector_type(4))) float v4f;

// round-to-nearest-even bf16 split: v = hi + lo (+O(2^-17) rel)
__device__ __forceinline__ void bsplit(float v, unsigned short& h, unsigned short& l) {
    unsigned u  = __builtin_bit_cast(unsigned, v);
    unsigned hb = (u + 0x7fffu + ((u >> 16) & 1u)) & 0xffff0000u;
    float hf    = __builtin_bit_cast(float, hb);
    h = (unsigned short)(hb >> 16);
    float lof   = v - hf;
    unsigned ul = __builtin_bit_cast(unsigned, lof);
    l = (unsigned short)((ul + 0x7fffu + ((ul >> 16) & 1u)) >> 16);
}

// async global->LDS, 16B per lane; LDS dest = wave-uniform base + lane*16
__device__ __forceinline__ void gl_lds16(const unsigned short* g, unsigned short* l) {
    __builtin_amdgcn_global_load_lds(
        (const __attribute__((address_space(1))) void*)g,
        (__attribute__((address_space(3))) void*)l, 16, 0, 0);
}

template<int N>
__device__ __forceinline__ void vmwait() {
    asm volatile("s_waitcnt vmcnt(%0)" :: "n"(N) : "memory");
}

// Fragment-tile layout for an [n][k] operand (n = MFMA 16-dim, k = K dim):
//   addr(shorts) = ((n/16)*(Kext/32) + k/32)*512 + ((n%16) + 16*((k%32)/8))*8 + k%8
// A wave's B-fragment load (n = base+m0, k = ko+quad*8) is ONE contiguous
// 1KB load at tile*512 + lane*8.
__device__ __forceinline__ size_t fragaddr(int n, int k, int kext) {
    return ((size_t)(n >> 4) * (kext >> 5) + (k >> 5)) * 512
         + (size_t)(((n & 15) + 16 * ((k >> 3) & 3)) * 8 + (k & 7));
}

// ---------------- degree: dinv[bc][i] = rsqrt(1 + sum_j adj[bc][i][j]) -----
__global__ __launch_bounds__(256) void k_rowsum(const float* __restrict__ adj,
                                                float* __restrict__ dinv) {
    int wave = blockIdx.x * 4 + (threadIdx.x >> 6);
    int lane = threadIdx.x & 63;
    const float4* row = (const float4*)(adj + (size_t)wave * NN);
    float4 v0 = row[lane], v1 = row[lane + 64];
    float s = v0.x + v0.y + v0.z + v0.w + v1.x + v1.y + v1.z + v1.w;
    #pragma unroll
    for (int off = 32; off; off >>= 1) s += __shfl_down(s, off, 64);
    if (lane == 0) dinv[wave] = rsqrtf(1.0f + s);
}

// ---------------- An = D(adj+I)D  ->  bf16 hi/lo planes (row-major) ---------
__global__ __launch_bounds__(256) void k_convert(const float* __restrict__ adj,
    const float* __restrict__ dinv, unsigned short* __restrict__ anh,
    unsigned short* __restrict__ anl)
{
    unsigned gid = blockIdx.x * 256 + threadIdx.x;
    unsigned e = gid * 4;               // element index, 4 per thread
    unsigned bc = e >> 18, rem = e & 0x3ffffu;
    unsigned i = rem >> 9, j = rem & 511u;
    float4 a = *(const float4*)(adj + (size_t)e);
    float di = dinv[bc * NN + i];
    const float4 dj = *(const float4*)(dinv + bc * NN + j);
    float v0 = di * dj.x * (a.x + ((j + 0) == i ? 1.f : 0.f));
    float v1 = di * dj.y * (a.y + ((j + 1) == i ? 1.f : 0.f));
    float v2 = di * dj.z * (a.z + ((j + 2) == i ? 1.f : 0.f));
    float v3 = di * dj.w * (a.w + ((j + 3) == i ? 1.f : 0.f));
    ushort4 hh, ll;
    bsplit(v0, hh.x, ll.x); bsplit(v1, hh.y, ll.y);
    bsplit(v2, hh.z, ll.z); bsplit(v3, hh.w, ll.w);
    *(ushort4*)(anh + e) = hh;
    *(ushort4*)(anl + e) = ll;
}

// ---------------- weight prep: split(w[p][h]); frag=1 -> fragment order -----
struct WJob  { const float* w; unsigned short* dh; unsigned short* dl; int HI; int HO; int HOP; int frag; };
struct WJobs { WJob j[8]; };
__global__ __launch_bounds__(256) void k_wprep(WJobs jobs) {
    WJob jb = jobs.j[blockIdx.y];
    int idx = blockIdx.x * 256 + threadIdx.x;
    if (idx >= jb.HOP * jb.HI) return;
    int h = idx / jb.HI, p = idx % jb.HI;
    float v = (h < jb.HO) ? jb.w[p * jb.HO + h] : 0.f;
    unsigned short hh, ll; bsplit(v, hh, ll);
    size_t oa = jb.frag ? fragaddr(h, p, jb.HI) : (size_t)idx;
    jb.dh[oa] = hh; jb.dl[oa] = ll;
}

// ---------------- MFMA layer: X = act(An @ Z + b) ---------------------------
// A: round-2 proven swizzled global_load_lds staging, depth-3 (NBUF=4, 32KB
//    LDS), counted vmcnt(4) (positional-safe: only A(kb+1),A(kb+2) guaranteed
//    younger), ONE raw s_barrier per K-step.
// Z: fragment-tile order in global (L2/L3-resident, shared across row-blocks)
//    -> direct 1KB coalesced register loads, double-buffered one step ahead.
//    No LDS for Z at all (Common-mistake #7: don't stage cache-fit data).
// Block = 64 rows x BN cols, 4 waves (2x2 for BN>=32, 4x1 for BN=16).
// 3-term split: Ah@Zh + Ah@Zl + Al@Zh (order preserved -> bit-identical).
template<int BN, int OUTW, bool SHAREDZ, bool ACT, bool WBF, int MINW>
__global__ __launch_bounds__(256, MINW) void k_mfma(
    const unsigned short* __restrict__ anh_, const unsigned short* __restrict__ anl_,
    const unsigned short* __restrict__ zh_,  const unsigned short* __restrict__ zl_,
    const float* __restrict__ bp, const float* __restrict__ bn,
    float* __restrict__ xf, unsigned short* __restrict__ xh, unsigned short* __restrict__ xl)
{
    constexpr int WC   = (BN >= 32) ? 2 : 1;      // col-split waves
    constexpr int WR   = 4 / WC;                  // row-split waves
    constexpr int RF   = 64 / (WR * 16);          // 16-row frags per wave
    constexpr int C    = (BN / WC) / 16;          // 16-col frags per wave
    constexpr int ASH  = 64 * 32;                 // shorts per A plane tile
    constexpr int NBUF = 4;                       // depth-3 prefetch
    __shared__ __align__(16) unsigned short smem[NBUF][2 * ASH];

    const int bc = blockIdx.y, rb = blockIdx.x;
    const int t = threadIdx.x, w = t >> 6, lane = t & 63;
    const int m0 = lane & 15, quad = lane >> 4;
    const int wr = w / WC, wcc = w % WC;
    const int s = SHAREDZ ? (bc & 1) : bc;

    // A staging source (round-2 swizzle: zero bank conflicts measured)
    const int arow = t >> 2;
    const int aslot = (t & 3) ^ ((arow >> 1) & 3);
    const unsigned short* ga_h = anh_ + ((size_t)bc * NN + (size_t)rb * 64 + arow) * NN + aslot * 8;
    const unsigned short* ga_l = anl_ + ((size_t)bc * NN + (size_t)rb * 64 + arow) * NN + aslot * 8;
    const int wbase = w * 512;

    // Z fragment pointers (fragment-tile order in global)
    const unsigned short* pzh[C]; const unsigned short* pzl[C];
    #pragma unroll
    for (int c = 0; c < C; ++c) {
        int nt = (wcc * (BN / WC)) / 16 + c;
        size_t zb = (size_t)s * BN * NN + (size_t)nt * (NN / 32) * 512 + (size_t)(lane * 8);
        pzh[c] = zh_ + zb; pzl[c] = zl_ + zb;
    }

    // A fragment read offsets (swizzle matches staging)
    int ra[RF];
    #pragma unroll
    for (int r = 0; r < RF; ++r) {
        int rho = wr * (RF * 16) + r * 16 + m0;
        ra[r] = rho * 32 + ((quad ^ ((rho >> 1) & 3)) * 8);
    }

    v4f acc[RF][C];
    #pragma unroll
    for (int r = 0; r < RF; ++r)
        #pragma unroll
        for (int c = 0; c < C; ++c) acc[r][c] = (v4f){0.f, 0.f, 0.f, 0.f};

    auto STAGE = [&](int b, int kb) {
        const int ko = kb * 32;
        gl_lds16(ga_h + ko, &smem[b][0] + wbase);
        gl_lds16(ga_l + ko, &smem[b][ASH] + wbase);
    };

    // prologue: A depth-3, Z(0) into registers
    STAGE(0, 0); STAGE(1, 1); STAGE(2, 2);
    asm volatile("" ::: "memory");                // pin z(0) after A stages
    v8bf zrh[2][C], zrl[2][C];
    #pragma unroll
    for (int c = 0; c < C; ++c) { zrh[0][c] = *(const v8bf*)(pzh[c]); zrl[0][c] = *(const v8bf*)(pzl[c]); }

    #pragma unroll
    for (int kb = 0; kb < 16; ++kb) {
        if (kb <= 13)      vmwait<4>();           // A(kb) landed (A(kb+1),A(kb+2) younger)
        else if (kb == 14) vmwait<2>();
        else               vmwait<0>();
        __builtin_amdgcn_s_barrier();             // all waves' tile-kb parts in
        asm volatile("" ::: "memory");
        if (kb + 3 < 16) STAGE((kb + 3) & 3, kb + 3);   // buf (kb-1)&3: reads done pre-barrier
        const int cur = kb & 1, nxt = cur ^ 1;
        if (kb + 1 < 16) {                        // Z prefetch one step ahead
            #pragma unroll
            for (int c = 0; c < C; ++c) {
                zrh[nxt][c] = *(const v8bf*)(pzh[c] + (kb + 1) * 512);
                zrl[nxt][c] = *(const v8bf*)(pzl[c] + (kb + 1) * 512);
            }
        }
        const unsigned short* bs = &smem[kb & 3][0];
        #pragma unroll
        for (int r = 0; r < RF; ++r) {
            v8bf ah = *(const v8bf*)(bs + ra[r]);
            v8bf al = *(const v8bf*)(bs + ASH + ra[r]);
            #pragma unroll
            for (int c = 0; c < C; ++c) {
                acc[r][c] = __builtin_amdgcn_mfma_f32_16x16x32_bf16(ah, zrh[cur][c], acc[r][c], 0, 0, 0);
                acc[r][c] = __builtin_amdgcn_mfma_f32_16x16x32_bf16(ah, zrl[cur][c], acc[r][c], 0, 0, 0);
                acc[r][c] = __builtin_amdgcn_mfma_f32_16x16x32_bf16(al, zrh[cur][c], acc[r][c], 0, 0, 0);
            }
        }
    }

    const float* bias = (bc & 1) ? bn : bp;
    #pragma unroll
    for (int r = 0; r < RF; ++r)
        #pragma unroll
        for (int c = 0; c < C; ++c) {
            int col = wcc * (BN / WC) + c * 16 + m0;
            if (OUTW < BN && col >= OUTW) continue;
            float bv = bias[col];
            #pragma unroll
            for (int reg = 0; reg < 4; ++reg) {
                int row = rb * 64 + wr * (RF * 16) + r * 16 + quad * 4 + reg;
                float v = acc[r][c][reg] + bv;
                if (ACT) v = v >= 0.f ? v : 0.2f * v;
                size_t oi = ((size_t)bc * NN + row) * OUTW + col;
                if (xf) xf[oi] = v;
                if (WBF) {
                    unsigned short hh, ll; bsplit(v, hh, ll);
                    xh[oi] = hh; xl[oi] = ll;
                }
            }
        }
}

// ---------------- MFMA Z-gemm: Zt[h][j] = sum_p W[p][h] X[j][p] -------------
// A = Wt [s][h][p] row-major, B = X [bc][j][p] row-major; output written in
// FRAGMENT-TILE order (n=h, k=j) for the next k_mfma's direct Z loads.
template<int HI, int HOP>
__global__ __launch_bounds__(256) void k_zgemm(
    const unsigned short* __restrict__ wth, const unsigned short* __restrict__ wtl,
    const unsigned short* __restrict__ xh_, const unsigned short* __restrict__ xl_,
    unsigned short* __restrict__ zh_, unsigned short* __restrict__ zl_)
{
    constexpr int MT = HOP / 16, JW = 4 / MT, NT = 8 / JW;
    const int bc = blockIdx.y, jb = blockIdx.x;
    const int t = threadIdx.x, w = t >> 6, lane = t & 63;
    const int m0 = lane & 15, quad = lane >> 4;
    const int mt = w % MT, jseg = w / MT;
    const int n0 = jb * 128 + jseg * (128 / JW);
    const int s = bc & 1;
    const unsigned short* pw_h = wth + ((size_t)s * HOP + mt * 16 + m0) * HI + quad * 8;
    const unsigned short* pw_l = wtl + ((size_t)s * HOP + mt * 16 + m0) * HI + quad * 8;
    const unsigned short* px_h = xh_ + ((size_t)bc * NN + n0 + m0) * HI + quad * 8;
    const unsigned short* px_l = xl_ + ((size_t)bc * NN + n0 + m0) * HI + quad * 8;
    v4f acc[NT];
    #pragma unroll
    for (int c = 0; c < NT; ++c) acc[c] = (v4f){0.f, 0.f, 0.f, 0.f};
    #pragma unroll
    for (int ks = 0; ks < HI / 32; ++ks) {
        const int ko = ks * 32;
        v8bf awh = *(const v8bf*)(pw_h + ko);
        v8bf awl = *(const v8bf*)(pw_l + ko);
        #pragma unroll
        for (int c = 0; c < NT; ++c) {
            v8bf bxh = *(const v8bf*)(px_h + (size_t)(c * 16) * HI + ko);
            v8bf bxl = *(const v8bf*)(px_l + (size_t)(c * 16) * HI + ko);
            acc[c] = __builtin_amdgcn_mfma_f32_16x16x32_bf16(awh, bxh, acc[c], 0, 0, 0);
            acc[c] = __builtin_amdgcn_mfma_f32_16x16x32_bf16(awh, bxl, acc[c], 0, 0, 0);
            acc[c] = __builtin_amdgcn_mfma_f32_16x16x32_bf16(awl, bxh, acc[c], 0, 0, 0);
        }
    }
    #pragma unroll
    for (int c = 0; c < NT; ++c) {
        int j = n0 + c * 16 + m0;
        #pragma unroll
        for (int reg = 0; reg < 4; ++reg) {
            int h = mt * 16 + quad * 4 + reg;
            unsigned short hh, ll; bsplit(acc[c][reg], hh, ll);
            size_t oi = (size_t)bc * HOP * NN + fragaddr(h, j, NN);
            zh_[oi] = hh; zl_[oi] = ll;
        }
    }
}

// ================= FALLBACK (R2 proven path, fp32 vector) ===================
template<int H, int HP, bool SHARED, bool ACT>
__global__ __launch_bounds__(256) void k_biggemm(
    const float* __restrict__ adj, const float* __restrict__ zcg,
    const float* __restrict__ wp, const float* __restrict__ wn,
    const float* __restrict__ bp, const float* __restrict__ bn,
    const float* __restrict__ dinv, float* __restrict__ xout)
{
    constexpr int CPT = HP / 16;
    constexpr int KT = 64;
    __shared__ float a_s[64 * 68];
    __shared__ float z_s[KT * H];
    const int bc = blockIdx.y;
    const int rt = blockIdx.x;
    const int t  = threadIdx.x;
    const int tx = t & 15, ty = t >> 4;
    const float* A    = adj + (size_t)bc * NN * NN + (size_t)rt * 64 * NN;
    const float* dloc = dinv + bc * NN;
    const float* ZG   = SHARED ? ((bc & 1) ? wn : wp) : (zcg + (size_t)bc * NN * H);
    const float* bias = (bc & 1) ? bn : bp;
    float acc[4][CPT];
    #pragma unroll
    for (int r = 0; r < 4; ++r)
        #pragma unroll
        for (int u = 0; u < CPT; ++u) acc[r][u] = 0.f;
    for (int kb = 0; kb < NN; kb += KT) {
        __syncthreads();
        #pragma unroll
        for (int l = 0; l < 4; ++l) {
            int idx = t + l * 256;
            int r = idx >> 4, q = idx & 15;
            float4 v = *(const float4*)(A + (size_t)r * NN + kb + q * 4);
            *(float4*)(a_s + r * 68 + q * 4) = v;
        }
        constexpr int NZ4 = KT * H / 4;
        for (int idx = t; idx < NZ4; idx += 256) {
            int k = idx / (H / 4), hq = idx % (H / 4);
            float4 v = *(const float4*)(ZG + (size_t)(kb + k) * H + hq * 4);
            if (SHARED) {
                float dk = dloc[kb + k];
                v.x *= dk; v.y *= dk; v.z *= dk; v.w *= dk;
            }
            *(float4*)(z_s + k * H + hq * 4) = v;
        }
        __syncthreads();
        #pragma unroll 8
        for (int k = 0; k < KT; ++k) {
            float ar[4];
            #pragma unroll
            for (int r = 0; r < 4; ++r) ar[r] = a_s[(ty * 4 + r) * 68 + k];
            float zv[CPT];
            #pragma unroll
            for (int u = 0; u < CPT; ++u) {
                int h = tx * CPT + u;
                if (H < HP && h >= H) h = 0;
                zv[u] = z_s[k * H + h];
            }
            #pragma unroll
            for (int r = 0; r < 4; ++r)
                #pragma unroll
                for (int u = 0; u < CPT; ++u)
                    acc[r][u] += ar[r] * zv[u];
        }
    }
    #pragma unroll
    for (int r = 0; r < 4; ++r) {
        int i = rt * 64 + ty * 4 + r;
        float di = dloc[i];
        #pragma unroll
        for (int u = 0; u < CPT; ++u) {
            int h = tx * CPT + u;
            if (H < HP && h >= H) continue;
            float self = SHARED ? di * ZG[(size_t)i * H + h] : ZG[(size_t)i * H + h];
            float v = di * (acc[r][u] + self) + bias[h];
            if (ACT) v = v >= 0.f ? v : 0.2f * v;
            xout[((size_t)bc * NN + i) * H + h] = v;
        }
    }
}

template<int HI, int HO>
__global__ __launch_bounds__(256) void k_smallgemm(
    const float* __restrict__ xin, const float* __restrict__ wp,
    const float* __restrict__ wn, const float* __restrict__ dinv,
    float* __restrict__ zc)
{
    constexpr int CPT = (HO >= 16) ? HO / 16 : 1;
    constexpr int XS = HI + 4;
    __shared__ float x_s[32 * XS];
    __shared__ float w_s[HI * HO];
    const int bc = blockIdx.y, jt = blockIdx.x, t = threadIdx.x;
    const int tx = t & 15, ty = t >> 4;
    const float* W = (bc & 1) ? wn : wp;
    const float* X = xin + ((size_t)bc * NN + jt * 32) * HI;
    for (int idx = t; idx < HI * HO / 4; idx += 256)
        *(float4*)(w_s + idx * 4) = *(const float4*)(W + idx * 4);
    for (int idx = t; idx < 32 * HI / 4; idx += 256) {
        int r = idx / (HI / 4), q = idx % (HI / 4);
        *(float4*)(x_s + r * XS + q * 4) = *(const float4*)(X + (size_t)r * HI + q * 4);
    }
    __syncthreads();
    float acc[2][CPT];
    #pragma unroll
    for (int r = 0; r < 2; ++r)
        #pragma unroll
        for (int u = 0; u < CPT; ++u) acc[r][u] = 0.f;
    #pragma unroll 4
    for (int p = 0; p < HI; ++p) {
        float xr[2];
        #pragma unroll
        for (int r = 0; r < 2; ++r) xr[r] = x_s[(ty * 2 + r) * XS + p];
        float wv[CPT];
        #pragma unroll
        for (int u = 0; u < CPT; ++u) {
            int h = tx * CPT + u;
            if (HO < 16 && h >= HO) h = 0;
            wv[u] = w_s[p * HO + h];
        }
        #pragma unroll
        for (int r = 0; r < 2; ++r)
            #pragma unroll
            for (int u = 0; u < CPT; ++u) acc[r][u] += xr[r] * wv[u];
    }
    const float* dloc = dinv + bc * NN;
    #pragma unroll
    for (int r = 0; r < 2; ++r) {
        int j = jt * 32 + ty * 2 + r;
        float dj = dloc[j];
        #pragma unroll
        for (int u = 0; u < CPT; ++u) {
            int h = tx * CPT + u;
            if (HO < 16 && h >= HO) continue;
            zc[((size_t)bc * NN + j) * HO + h] = dj * acc[r][u];
        }
    }
}

// ---------------- DCL head (shared by both paths) ---------------------------
__global__ __launch_bounds__(256) void k_dcl(
    const float* __restrict__ x3, const float* __restrict__ x4,
    const float* __restrict__ wc, const int* __restrict__ task,
    float* __restrict__ L)
{
    __shared__ float ps[8][32];
    __shared__ float xf[32];
    __shared__ float pr[72];
    const int bc = blockIdx.x, t = threadIdx.x;
    const float* X3 = x3 + (size_t)bc * NN * 32;
    {
        int col = t & 31, rg = t >> 5;
        float s = 0.f;
        for (int r = rg; r < NN; r += 8) s += X3[r * 32 + col];
        ps[rg][col] = s;
    }
    __syncthreads();
    if (t < 32) {
        float s = 0.f;
        #pragma unroll
        for (int g = 0; g < 8; ++g) s += ps[g][t];
        xf[t] = s * (1.0f / 512.0f);
    }
    __syncthreads();
    if (t < 72) {
        int tid = task[bc >> 1];
        const float* wr = wc + t * 48;
        float s = wr[32 + tid];
        #pragma unroll
        for (int j = 0; j < 32; ++j) s += wr[j] * xf[j];
        pr[t] = s;
    }
    __syncthreads();
    const float* X4 = x4 + (size_t)bc * 4096;
    float* Lb = L + (size_t)bc * 4096;
    #pragma unroll
    for (int rep = 0; rep < 2; ++rep) {
        int n = rep * 256 + t;
        float hi[8];
        #pragma unroll
        for (int i = 0; i < 8; ++i) hi[i] = X4[i * 512 + n];
        #pragma unroll
        for (int o = 0; o < 8; ++o) {
            float s = pr[64 + o];
            #pragma unroll
            for (int i = 0; i < 8; ++i) s += pr[o * 8 + i] * hi[i];
            Lb[o * 512 + n] = s;
        }
    }
}

// ---------------- final: out[bc][n][m] = softplus(-cc_n . cc_m) -------------
#define SCP 520
__global__ __launch_bounds__(256) void k_final(const float* __restrict__ L,
                                               float* __restrict__ out)
{
    __shared__ float scT[8 * SCP];
    const int bcid = blockIdx.y;
    const int b = bcid >> 1, c = bcid & 1;
    const int nt = blockIdx.x, t = threadIdx.x;
    const float* Lp = L + (size_t)(b * 2) * 4096;
    const float* Ln = Lp + 4096;
    for (int rep = 0; rep < 16; ++rep) {
        int e = rep * 256 + t;
        int f = c * 4096 + e;
        int n = f >> 4, k = f & 15;
        float v = (k < 8) ? Lp[n * 8 + k] : Ln[n * 8 + k - 8];
        scT[(e & 7) * SCP + (e >> 3)] = v;
    }
    __syncthreads();
    const int tx = t & 63, ty = t >> 6;
    const int n0 = nt * 32 + ty * 8;
    float cn[8][8];
    #pragma unroll
    for (int o = 0; o < 8; ++o)
        #pragma unroll
        for (int i = 0; i < 8; ++i) cn[i][o] = scT[o * SCP + n0 + i];
    float* ob = out + (size_t)bcid * NN * NN;
    #pragma unroll 2
    for (int mg = 0; mg < 8; ++mg) {
        int m = tx + mg * 64;
        float cm[8];
        #pragma unroll
        for (int o = 0; o < 8; ++o) cm[o] = scT[o * SCP + m];
        #pragma unroll
        for (int i = 0; i < 8; ++i) {
            float s = 0.f;
            #pragma unroll
            for (int o = 0; o < 8; ++o) s += cn[i][o] * cm[o];
            float r = fmaxf(-s, 0.f) + __logf(1.0f + __expf(-fabsf(s)));
            ob[(size_t)(n0 + i) * NN + m] = r;
        }
    }
}

extern "C" void kernel_launch(void* const* d_in, const int* in_sizes, int n_in,
                              void* d_out, int out_size, void* d_ws, size_t ws_size,
                              hipStream_t stream)
{
    const float* adj = (const float*)d_in[0];
    const int*  task = (const int*)d_in[1];
    const float* w1p = (const float*)d_in[2];  const float* b1p = (const float*)d_in[3];
    const float* w2p = (const float*)d_in[4];  const float* b2p = (const float*)d_in[5];
    const float* w3p = (const float*)d_in[6];  const float* b3p = (const float*)d_in[7];
    const float* w4p = (const float*)d_in[8];  const float* b4p = (const float*)d_in[9];
    const float* w1n = (const float*)d_in[10]; const float* b1n = (const float*)d_in[11];
    const float* w2n = (const float*)d_in[12]; const float* b2n = (const float*)d_in[13];
    const float* w3n = (const float*)d_in[14]; const float* b3n = (const float*)d_in[15];
    const float* w4n = (const float*)d_in[16]; const float* b4n = (const float*)d_in[17];
    const float* wc  = (const float*)d_in[18];
    (void)in_sizes; (void)n_in; (void)out_size;

    const size_t NEED = 198004736ull;
    if (ws_size >= NEED) {
        char* base = (char*)d_ws;
        float*          dinv = (float*)(base + 0);
        unsigned short* anh  = (unsigned short*)(base + 262144);
        unsigned short* anl  = (unsigned short*)(base + 67371008);
        unsigned short* zt1h = (unsigned short*)(base + 134479872);
        unsigned short* zt1l = (unsigned short*)(base + 134742016);
        unsigned short* wt2h = (unsigned short*)(base + 135004160);
        unsigned short* wt2l = (unsigned short*)(base + 135036928);
        unsigned short* wt3h = (unsigned short*)(base + 135069696);
        unsigned short* wt3l = (unsigned short*)(base + 135077888);
        unsigned short* wt4h = (unsigned short*)(base + 135086080);
        unsigned short* wt4l = (unsigned short*)(base + 135088128);
        unsigned short* x1h  = (unsigned short*)(base + 135090176);
        unsigned short* x1l  = (unsigned short*)(base + 151867392);
        unsigned short* zt2h = (unsigned short*)(base + 168644608);
        unsigned short* zt2l = (unsigned short*)(base + 177033216);
        float*          x3f  = (float*)(base + 185421824);
        float*          x4f  = (float*)(base + 193810432);
        float*          L    = (float*)(base + 195907584);
        // aliases (lifetimes disjoint across kernel boundaries)
        unsigned short* x2h = x1h,  *x2l = x1l;
        unsigned short* x3h = x1h,  *x3l = x1l;
        unsigned short* zt3h = zt2h, *zt3l = zt2l;
        unsigned short* zt4h = zt2h, *zt4l = zt2l;

        k_rowsum<<<dim3(NBC * NN / 4), 256, 0, stream>>>(adj, dinv);
        k_convert<<<dim3(32768), 256, 0, stream>>>(adj, dinv, anh, anl);
        WJobs jobs;
        jobs.j[0] = {w1p, zt1h,          zt1l,          512, 128, 128, 1};
        jobs.j[1] = {w1n, zt1h + 65536,  zt1l + 65536,  512, 128, 128, 1};
        jobs.j[2] = {w2p, wt2h,          wt2l,          128,  64,  64, 0};
        jobs.j[3] = {w2n, wt2h + 8192,   wt2l + 8192,   128,  64,  64, 0};
        jobs.j[4] = {w3p, wt3h,          wt3l,           64,  32,  32, 0};
        jobs.j[5] = {w3n, wt3h + 2048,   wt3l + 2048,    64,  32,  32, 0};
        jobs.j[6] = {w4p, wt4h,          wt4l,           32,   8,  16, 0};
        jobs.j[7] = {w4n, wt4h + 512,    wt4l + 512,     32,   8,  16, 0};
        k_wprep<<<dim3(256, 8), 256, 0, stream>>>(jobs);

        k_mfma<128, 128, true,  true,  true,  3><<<dim3(8, NBC), 256, 0, stream>>>(
            anh, anl, zt1h, zt1l, b1p, b1n, nullptr, x1h, x1l);
        k_zgemm<128, 64><<<dim3(4, NBC), 256, 0, stream>>>(wt2h, wt2l, x1h, x1l, zt2h, zt2l);
        k_mfma<64, 64, false, true,  true,  4><<<dim3(8, NBC), 256, 0, stream>>>(
            anh, anl, zt2h, zt2l, b2p, b2n, nullptr, x2h, x2l);
        k_zgemm<64, 32><<<dim3(4, NBC), 256, 0, stream>>>(wt3h, wt3l, x2h, x2l, zt3h, zt3l);
        k_mfma<32, 32, false, true,  true,  4><<<dim3(8, NBC), 256, 0, stream>>>(
            anh, anl, zt3h, zt3l, b3p, b3n, x3f, x3h, x3l);
        k_zgemm<32, 16><<<dim3(4, NBC), 256, 0, stream>>>(wt4h, wt4l, x3h, x3l, zt4h, zt4l);
        k_mfma<16, 8, false, false, false, 4><<<dim3(8, NBC), 256, 0, stream>>>(
            anh, anl, zt4h, zt4l, b4p, b4n, x4f, nullptr, nullptr);
        k_dcl<<<dim3(NBC), 256, 0, stream>>>(x3f, x4f, wc, task, L);
        k_final<<<dim3(16, NBC), 256, 0, stream>>>(L, (float*)d_out);
    } else {
        // -------- fallback: proven R2 fp32 path (needs ~63 MB) --------
        float* ws   = (float*)d_ws;
        float* dinv = ws;
        float* XA   = ws + 65536;
        float* X3   = XA + 8388608;
        float* X4   = X3 + 2097152;
        float* L    = X4 + 524288;
        float* ZC   = L  + 524288;
        k_rowsum<<<dim3(NBC * NN / 4), 256, 0, stream>>>(adj, dinv);
        k_biggemm<128,128,true ,true ><<<dim3(8,128), 256, 0, stream>>>(adj, nullptr, w1p, w1n, b1p, b1n, dinv, XA);
        k_smallgemm<128,64><<<dim3(16,128), 256, 0, stream>>>(XA, w2p, w2n, dinv, ZC);
        k_biggemm<64,64,false,true ><<<dim3(8,128), 256, 0, stream>>>(adj, ZC, nullptr, nullptr, b2p, b2n, dinv, XA);
        k_smallgemm<64,32><<<dim3(16,128), 256, 0, stream>>>(XA, w3p, w3n, dinv, ZC);
        k_biggemm<32,32,false,true ><<<dim3(8,128), 256, 0, stream>>>(adj, ZC, nullptr, nullptr, b3p, b3n, dinv, X3);
        k_smallgemm<32,8><<<dim3(16,128), 256, 0, stream>>>(X3, w4p, w4n, dinv, ZC);
        k_biggemm<8,16,false,false><<<dim3(8,128), 256, 0, stream>>>(adj, ZC, nullptr, nullptr, b4p, b4n, dinv, X4);
        k_dcl<<<dim3(128), 256, 0, stream>>>(X3, X4, wc, task, L);
        k_final<<<dim3(16,128), 256, 0, stream>>>(L, (float*)d_out);
    }
}